// Round 1
// baseline (219.724 us; speedup 1.0000x reference)
//
#include <hip/hip_runtime.h>
#include <math.h>

#define Bn   1024
#define Fdim 256
#define Nn   65536
#define Cn   1000
#define INV_TEMP 20.0f
#define MOM  0.2f

// ---------------- workspace layout (all 4-byte types, no padding) ----------
struct WS {
  float x[Bn * Fdim];       // normalized inputs           (1 MB)
  float meanT[Fdim * Cn];   // class means, [f][c] layout  (1 MB)
  float mask[Cn];
  float sumExp[Bn];
  float tExp[Bn];
  int   idx[Bn];
  int   targets[Bn];
  int   counts[Cn];
  int   offsets[Cn];
  int   cursor[Cn];
  int   list[Nn];
};

// K0: zero the atomically-accumulated buffers (ws is poisoned 0xAA each call)
__global__ void k0_zero(int* __restrict__ counts, float* __restrict__ sumExp) {
  int t = blockIdx.x * blockDim.x + threadIdx.x;
  if (t < Cn) counts[t] = 0;
  if (t < Bn) sumExp[t] = 0.f;
}

// K1: x = inputs / ||inputs||, plus idx remap and targets
__global__ void k1_norm(const float* __restrict__ inputs, const int* __restrict__ indexes,
                        const int* __restrict__ labels, float* __restrict__ x,
                        int* __restrict__ idx, int* __restrict__ targets) {
  int b = blockIdx.x, t = threadIdx.x;
  float v = inputs[b * Fdim + t];
  float s = v * v;
#pragma unroll
  for (int o = 32; o > 0; o >>= 1) s += __shfl_down(s, o, 64);
  __shared__ float red[4];
  if ((t & 63) == 0) red[t >> 6] = s;
  __syncthreads();
  float tot = red[0] + red[1] + red[2] + red[3];
  float inv = 1.0f / sqrtf(tot);
  x[b * Fdim + t] = v * inv;
  if (t == 0) {
    int i0 = indexes[b] - 1;
    if (i0 == 5554) i0 = 750;   // is_source special case -> SOURCE_CLASSES-1
    idx[b] = i0;
    targets[b] = labels[i0];
  }
}

// K2: histogram of labels
__global__ void k2_count(const int* __restrict__ labels, int* __restrict__ counts) {
  int n = blockIdx.x * blockDim.x + threadIdx.x;
  atomicAdd(&counts[labels[n]], 1);
}

// K3: exclusive scan of counts -> offsets, cursor (single block, 1024 threads)
__global__ void k3_scan(const int* __restrict__ counts, int* __restrict__ offsets,
                        int* __restrict__ cursor) {
  __shared__ int s[1024];
  int t = threadIdx.x;
  int v = (t < Cn) ? counts[t] : 0;
  s[t] = v;
  __syncthreads();
  for (int o = 1; o < 1024; o <<= 1) {
    int a = (t >= o) ? s[t - o] : 0;
    __syncthreads();
    s[t] += a;
    __syncthreads();
  }
  if (t < Cn) {
    int off = s[t] - v;
    offsets[t] = off;
    cursor[t] = off;
  }
}

// K4: fill per-class member lists
__global__ void k4_fill(const int* __restrict__ labels, int* __restrict__ cursor,
                        int* __restrict__ list) {
  int n = blockIdx.x * blockDim.x + threadIdx.x;
  int c = labels[n];
  int p = atomicAdd(&cursor[c], 1);
  list[p] = n;
}

// K5: one block per class: gather member rows -> class mean (transposed store),
//     and simultaneously copy every feature row to out+1 (each row is in exactly
//     one class list, so this covers the whole bank).
__global__ void k5_classsum(const float* __restrict__ features, const int* __restrict__ list,
                            const int* __restrict__ offsets, const int* __restrict__ counts,
                            float* __restrict__ meanT, float* __restrict__ mask,
                            float* __restrict__ out1) {
  int c = blockIdx.x, t = threadIdx.x;
  int off = offsets[c], cnt = counts[c];
  __shared__ int mlds[256];
  float acc = 0.f;
  for (int base = 0; base < cnt; base += 256) {
    int m = min(256, cnt - base);
    if (t < m) mlds[t] = list[off + base + t];
    __syncthreads();
    int i = 0;
    for (; i + 4 <= m; i += 4) {
      int n0 = mlds[i], n1 = mlds[i + 1], n2 = mlds[i + 2], n3 = mlds[i + 3];
      float v0 = features[n0 * Fdim + t];
      float v1 = features[n1 * Fdim + t];
      float v2 = features[n2 * Fdim + t];
      float v3 = features[n3 * Fdim + t];
      acc += v0 + v1 + v2 + v3;
      out1[n0 * Fdim + t] = v0;
      out1[n1 * Fdim + t] = v1;
      out1[n2 * Fdim + t] = v2;
      out1[n3 * Fdim + t] = v3;
    }
    for (; i < m; i++) {
      int n = mlds[i];
      float v = features[n * Fdim + t];
      acc += v;
      out1[n * Fdim + t] = v;
    }
    __syncthreads();
  }
  meanT[t * Cn + c] = (cnt > 0) ? acc / (float)cnt : 0.f;
  if (t == 0) mask[c] = (cnt > 0) ? 1.f : 0.f;
}

// K6: sim = (x @ classMean^T)/TEMP fused with masked-softmax partials:
//     per-row sum of exps (atomic) and the exp at the target class.
#define BBT 8
__global__ void k6_matmul(const float* __restrict__ x, const float* __restrict__ meanT,
                          const float* __restrict__ mask, const int* __restrict__ targets,
                          float* __restrict__ sumExp, float* __restrict__ tExp) {
  int b0 = blockIdx.x * BBT, c0 = blockIdx.y * 256;
  int t = threadIdx.x;
  __shared__ float xs[BBT][Fdim];
#pragma unroll
  for (int bb = 0; bb < BBT; bb++) xs[bb][t] = x[(b0 + bb) * Fdim + t];
  __syncthreads();
  int c = c0 + t;
  bool cv = (c < Cn);
  float acc[BBT];
#pragma unroll
  for (int bb = 0; bb < BBT; bb++) acc[bb] = 0.f;
  for (int f = 0; f < Fdim; f += 4) {
    float mv0 = cv ? meanT[(f + 0) * Cn + c] : 0.f;
    float mv1 = cv ? meanT[(f + 1) * Cn + c] : 0.f;
    float mv2 = cv ? meanT[(f + 2) * Cn + c] : 0.f;
    float mv3 = cv ? meanT[(f + 3) * Cn + c] : 0.f;
#pragma unroll
    for (int bb = 0; bb < BBT; bb++) {
      float4 xv = *(const float4*)&xs[bb][f];   // wave-uniform LDS broadcast
      acc[bb] += xv.x * mv0 + xv.y * mv1 + xv.z * mv2 + xv.w * mv3;
    }
  }
  float msk = cv ? mask[c] : 0.f;
  __shared__ float red[4];
#pragma unroll 1
  for (int bb = 0; bb < BBT; bb++) {
    float e = msk * expf(acc[bb] * INV_TEMP);
    float s = e;
#pragma unroll
    for (int o = 32; o > 0; o >>= 1) s += __shfl_down(s, o, 64);
    if ((t & 63) == 0) red[t >> 6] = s;
    __syncthreads();
    if (t == 0) atomicAdd(&sumExp[b0 + bb], red[0] + red[1] + red[2] + red[3]);
    int tgt = targets[b0 + bb];
    if (cv && tgt == c) tExp[b0 + bb] = e;
    __syncthreads();
  }
}

// K7: final loss reduction (single block, 1024 threads = one per sample)
__global__ void k7_loss(const float* __restrict__ sumExp, const float* __restrict__ tExp,
                        const int* __restrict__ targets, float* __restrict__ out) {
  int t = threadIdx.x;
  float S = sumExp[t], tE = tExp[t];
  float nll = -logf(tE / (S + 1e-6f) + 1e-6f);
  float valid = (targets[t] != 750) ? 1.f : 0.f;
  float a = nll * valid, b = valid;
#pragma unroll
  for (int o = 32; o > 0; o >>= 1) {
    a += __shfl_down(a, o, 64);
    b += __shfl_down(b, o, 64);
  }
  __shared__ float ra[16], rb[16];
  if ((t & 63) == 0) { ra[t >> 6] = a; rb[t >> 6] = b; }
  __syncthreads();
  if (t == 0) {
    float sa = 0.f, sb = 0.f;
    for (int i = 0; i < 16; i++) { sa += ra[i]; sb += rb[i]; }
    out[0] = sa / fmaxf(sb, 1.f);
  }
}

// K8: sequential momentum scatter update. One wave per sample b; only the
// first occurrence of each index runs, processing its whole duplicate chain
// in ascending b order (matches the lax.scan semantics exactly).
__global__ __launch_bounds__(256) void k8_update(const float* __restrict__ features,
                                                 const float* __restrict__ x,
                                                 const int* __restrict__ idx,
                                                 float* __restrict__ out1) {
  __shared__ int ilds[Bn];
  int t = threadIdx.x;
  for (int i = t; i < Bn; i += 256) ilds[i] = idx[i];
  __syncthreads();
  int wid = t >> 6, lane = t & 63;
  int b = blockIdx.x * 4 + wid;
  int y = ilds[b];
  // am I the first occurrence of y?
  for (int base = 0; base < b; base += 64) {
    int j = base + lane;
    bool hit = (j < b) && (ilds[j] == y);
    if (__any(hit)) return;   // wave-uniform exit (no syncthreads below)
  }
  float4 r = *(const float4*)&features[y * Fdim + lane * 4];
  for (int base = (b >> 6) << 6; base < Bn; base += 64) {
    int k = base + lane;
    bool hit = (k >= b) && (ilds[k] == y);
    unsigned long long mbits = __ballot(hit);
    while (mbits) {
      int p = __ffsll(mbits) - 1;
      mbits &= mbits - 1;
      int kk = base + p;
      float4 xv = *(const float4*)&x[kk * Fdim + lane * 4];
      r.x = MOM * r.x + (1.f - MOM) * xv.x;
      r.y = MOM * r.y + (1.f - MOM) * xv.y;
      r.z = MOM * r.z + (1.f - MOM) * xv.z;
      r.w = MOM * r.w + (1.f - MOM) * xv.w;
      float ss = r.x * r.x + r.y * r.y + r.z * r.z + r.w * r.w;
#pragma unroll
      for (int o = 32; o > 0; o >>= 1) ss += __shfl_xor(ss, o, 64);
      float inv = 1.0f / sqrtf(ss);
      r.x *= inv; r.y *= inv; r.z *= inv; r.w *= inv;
    }
  }
  int base2 = y * Fdim + lane * 4;   // out1 is off+1 misaligned -> scalar stores
  out1[base2 + 0] = r.x;
  out1[base2 + 1] = r.y;
  out1[base2 + 2] = r.z;
  out1[base2 + 3] = r.w;
}

extern "C" void kernel_launch(void* const* d_in, const int* in_sizes, int n_in,
                              void* d_out, int out_size, void* d_ws, size_t ws_size,
                              hipStream_t stream) {
  const float* inputs   = (const float*)d_in[0];
  const int*   indexes  = (const int*)d_in[1];
  const float* features = (const float*)d_in[2];
  const int*   labels   = (const int*)d_in[3];
  float* out = (float*)d_out;          // out[0] = loss, out[1..] = new_features
  WS* w = (WS*)d_ws;

  k0_zero<<<4, 256, 0, stream>>>(w->counts, w->sumExp);
  k1_norm<<<Bn, 256, 0, stream>>>(inputs, indexes, labels, w->x, w->idx, w->targets);
  k2_count<<<Nn / 256, 256, 0, stream>>>(labels, w->counts);
  k3_scan<<<1, 1024, 0, stream>>>(w->counts, w->offsets, w->cursor);
  k4_fill<<<Nn / 256, 256, 0, stream>>>(labels, w->cursor, w->list);
  k5_classsum<<<Cn, 256, 0, stream>>>(features, w->list, w->offsets, w->counts,
                                      w->meanT, w->mask, out + 1);
  k6_matmul<<<dim3(Bn / BBT, 4), 256, 0, stream>>>(w->x, w->meanT, w->mask, w->targets,
                                                   w->sumExp, w->tExp);
  k7_loss<<<1, 1024, 0, stream>>>(w->sumExp, w->tExp, w->targets, out);
  k8_update<<<Bn / 4, 256, 0, stream>>>(features, w->x, w->idx, out + 1);
}

// Round 2
// 213.649 us; speedup vs baseline: 1.0284x; 1.0284x over previous
//
#include <hip/hip_runtime.h>
#include <math.h>

#define Bn   1024
#define Fdim 256
#define Nn   65536
#define Cn   1000
#define INV_TEMP 20.0f
#define MOM  0.2f

// ---------------- workspace layout (all 4-byte types, no padding) ----------
struct WS {
  float x[Bn * Fdim];       // normalized inputs                    (1 MB)
  float meanP[Fdim * Cn];   // class means, packed [F/4][Cn][4]     (1 MB)
  float mask[Cn];
  float sumExp[Bn];
  float tExp[Bn];
  int   idx[Bn];
  int   targets[Bn];
  int   counts[Cn];
  int   offsets[Cn];
  int   cursor[Cn];
  int   list[Nn];
};

// K0: zero the atomically-accumulated buffers (ws is poisoned 0xAA each call)
__global__ void k0_zero(int* __restrict__ counts, float* __restrict__ sumExp) {
  int t = blockIdx.x * blockDim.x + threadIdx.x;
  if (t < Cn) counts[t] = 0;
  if (t < Bn) sumExp[t] = 0.f;
}

// K1: x = inputs / ||inputs||, one wave per row, float4, no LDS
__global__ __launch_bounds__(64) void k1_norm(const float* __restrict__ inputs,
                                              const int* __restrict__ indexes,
                                              const int* __restrict__ labels,
                                              float* __restrict__ x,
                                              int* __restrict__ idx, int* __restrict__ targets) {
  int b = blockIdx.x, t = threadIdx.x;
  float4 v = *(const float4*)&inputs[b * Fdim + t * 4];
  float s = v.x * v.x + v.y * v.y + v.z * v.z + v.w * v.w;
#pragma unroll
  for (int o = 32; o > 0; o >>= 1) s += __shfl_xor(s, o, 64);
  float inv = 1.0f / sqrtf(s);
  v.x *= inv; v.y *= inv; v.z *= inv; v.w *= inv;
  *(float4*)&x[b * Fdim + t * 4] = v;
  if (t == 0) {
    int i0 = indexes[b] - 1;
    if (i0 == 5554) i0 = 750;   // is_source special case -> SOURCE_CLASSES-1
    idx[b] = i0;
    targets[b] = labels[i0];
  }
}

// K2: histogram of labels
__global__ void k2_count(const int* __restrict__ labels, int* __restrict__ counts) {
  int n = blockIdx.x * blockDim.x + threadIdx.x;
  atomicAdd(&counts[labels[n]], 1);
}

// K3: exclusive scan of counts -> offsets, cursor (single block, 1024 threads)
__global__ void k3_scan(const int* __restrict__ counts, int* __restrict__ offsets,
                        int* __restrict__ cursor) {
  __shared__ int s[1024];
  int t = threadIdx.x;
  int v = (t < Cn) ? counts[t] : 0;
  s[t] = v;
  __syncthreads();
  for (int o = 1; o < 1024; o <<= 1) {
    int a = (t >= o) ? s[t - o] : 0;
    __syncthreads();
    s[t] += a;
    __syncthreads();
  }
  if (t < Cn) {
    int off = s[t] - v;
    offsets[t] = off;
    cursor[t] = off;
  }
}

// K4: fill per-class member lists
__global__ void k4_fill(const int* __restrict__ labels, int* __restrict__ cursor,
                        int* __restrict__ list) {
  int n = blockIdx.x * blockDim.x + threadIdx.x;
  int c = labels[n];
  int p = atomicAdd(&cursor[c], 1);
  list[p] = n;
}

// K5: one block (8 waves) per class. Wave-per-row float4 gather: one
// global_load_dwordx4 covers a full 1KB feature row per wave. Accumulate class
// sum and simultaneously copy every row to out+1 (each row is in exactly one
// class list -> full bank coverage). 2-deep manual pipeline on the row loads.
__global__ __launch_bounds__(512) void k5_classsum(const float* __restrict__ features,
                                                   const int* __restrict__ list,
                                                   const int* __restrict__ offsets,
                                                   const int* __restrict__ counts,
                                                   float* __restrict__ meanP,
                                                   float* __restrict__ mask,
                                                   float* __restrict__ out1) {
  int c = blockIdx.x, t = threadIdx.x, w = t >> 6, lane = t & 63;
  int off = offsets[c], cnt = counts[c];
  __shared__ int mlds[512];
  __shared__ float partial[8][256];
  float4 acc = {0.f, 0.f, 0.f, 0.f};
  for (int base = 0; base < cnt; base += 512) {
    int m = min(512, cnt - base);
    if (t < m) mlds[t] = list[off + base + t];
    __syncthreads();
    int i = w;
    for (; i + 8 < m; i += 16) {   // two rows per wave per iteration
      int n0 = mlds[i], n1 = mlds[i + 8];
      float4 v0 = *(const float4*)&features[n0 * Fdim + lane * 4];
      float4 v1 = *(const float4*)&features[n1 * Fdim + lane * 4];
      acc.x += v0.x + v1.x; acc.y += v0.y + v1.y;
      acc.z += v0.z + v1.z; acc.w += v0.w + v1.w;
      float* o0 = &out1[n0 * Fdim + lane * 4];
      o0[0] = v0.x; o0[1] = v0.y; o0[2] = v0.z; o0[3] = v0.w;
      float* o1 = &out1[n1 * Fdim + lane * 4];
      o1[0] = v1.x; o1[1] = v1.y; o1[2] = v1.z; o1[3] = v1.w;
    }
    for (; i < m; i += 8) {
      int n = mlds[i];
      float4 v = *(const float4*)&features[n * Fdim + lane * 4];
      acc.x += v.x; acc.y += v.y; acc.z += v.z; acc.w += v.w;
      float* o = &out1[n * Fdim + lane * 4];
      o[0] = v.x; o[1] = v.y; o[2] = v.z; o[3] = v.w;
    }
    __syncthreads();
  }
  *(float4*)&partial[w][lane * 4] = acc;
  __syncthreads();
  if (t < 256) {
    float s = 0.f;
#pragma unroll
    for (int ww = 0; ww < 8; ww++) s += partial[ww][t];
    // packed layout: element (f=t, c) at [(f>>2)*Cn + c]*4 + (f&3)
    meanP[((t >> 2) * Cn + c) * 4 + (t & 3)] = (cnt > 0) ? s / (float)cnt : 0.f;
    if (t == 0) mask[c] = (cnt > 0) ? 1.f : 0.f;
  }
}

// K6: sim = (x @ classMean^T)/TEMP fused with masked-softmax partials.
// No LDS, no barriers. meanP packed so each thread's 4 f-elements are one
// coalesced dwordx4; x reads are block-uniform (scalar/broadcast loads).
#define BBT 8
__global__ __launch_bounds__(256) void k6_matmul(const float* __restrict__ x,
                                                 const float* __restrict__ meanP,
                                                 const float* __restrict__ mask,
                                                 const int* __restrict__ targets,
                                                 float* __restrict__ sumExp,
                                                 float* __restrict__ tExp) {
  int b0 = blockIdx.x * BBT;
  int c  = blockIdx.y * 256 + threadIdx.x;
  int lane = threadIdx.x & 63;
  bool cv = (c < Cn);
  int cc = cv ? c : 0;
  float acc[BBT];
#pragma unroll
  for (int bb = 0; bb < BBT; bb++) acc[bb] = 0.f;
  const float* xb = x + b0 * Fdim;
#pragma unroll 4
  for (int f4 = 0; f4 < Fdim / 4; f4++) {
    float4 mv = *(const float4*)&meanP[(f4 * Cn + cc) * 4];
#pragma unroll
    for (int bb = 0; bb < BBT; bb++) {
      float4 xv = *(const float4*)&xb[bb * Fdim + f4 * 4];   // uniform address
      acc[bb] = fmaf(xv.x, mv.x, acc[bb]);
      acc[bb] = fmaf(xv.y, mv.y, acc[bb]);
      acc[bb] = fmaf(xv.z, mv.z, acc[bb]);
      acc[bb] = fmaf(xv.w, mv.w, acc[bb]);
    }
  }
  float msk = cv ? mask[cc] : 0.f;
#pragma unroll
  for (int bb = 0; bb < BBT; bb++) {
    float e = msk * __expf(acc[bb] * INV_TEMP);
    float s = e;
#pragma unroll
    for (int o = 32; o > 0; o >>= 1) s += __shfl_down(s, o, 64);
    if (lane == 0) atomicAdd(&sumExp[b0 + bb], s);
    int tgt = targets[b0 + bb];
    if (cv && tgt == c) tExp[b0 + bb] = e;
  }
}

// K7: final loss reduction (single block, 1024 threads = one per sample)
__global__ void k7_loss(const float* __restrict__ sumExp, const float* __restrict__ tExp,
                        const int* __restrict__ targets, float* __restrict__ out) {
  int t = threadIdx.x;
  float S = sumExp[t], tE = tExp[t];
  float nll = -logf(tE / (S + 1e-6f) + 1e-6f);
  float valid = (targets[t] != 750) ? 1.f : 0.f;
  float a = nll * valid, b = valid;
#pragma unroll
  for (int o = 32; o > 0; o >>= 1) {
    a += __shfl_down(a, o, 64);
    b += __shfl_down(b, o, 64);
  }
  __shared__ float ra[16], rb[16];
  if ((t & 63) == 0) { ra[t >> 6] = a; rb[t >> 6] = b; }
  __syncthreads();
  if (t == 0) {
    float sa = 0.f, sb = 0.f;
    for (int i = 0; i < 16; i++) { sa += ra[i]; sb += rb[i]; }
    out[0] = sa / fmaxf(sb, 1.f);
  }
}

// K8: sequential momentum scatter update. One wave per sample b; only the
// first occurrence of each index runs, processing its whole duplicate chain
// in ascending b order (matches the lax.scan semantics exactly).
__global__ __launch_bounds__(256) void k8_update(const float* __restrict__ features,
                                                 const float* __restrict__ x,
                                                 const int* __restrict__ idx,
                                                 float* __restrict__ out1) {
  __shared__ int ilds[Bn];
  int t = threadIdx.x;
  for (int i = t; i < Bn; i += 256) ilds[i] = idx[i];
  __syncthreads();
  int wid = t >> 6, lane = t & 63;
  int b = blockIdx.x * 4 + wid;
  int y = ilds[b];
  // am I the first occurrence of y?
  for (int base = 0; base < b; base += 64) {
    int j = base + lane;
    bool hit = (j < b) && (ilds[j] == y);
    if (__any(hit)) return;   // wave-uniform exit (no syncthreads below)
  }
  float4 r = *(const float4*)&features[y * Fdim + lane * 4];
  for (int base = (b >> 6) << 6; base < Bn; base += 64) {
    int k = base + lane;
    bool hit = (k >= b) && (ilds[k] == y);
    unsigned long long mbits = __ballot(hit);
    while (mbits) {
      int p = __ffsll(mbits) - 1;
      mbits &= mbits - 1;
      int kk = base + p;
      float4 xv = *(const float4*)&x[kk * Fdim + lane * 4];
      r.x = MOM * r.x + (1.f - MOM) * xv.x;
      r.y = MOM * r.y + (1.f - MOM) * xv.y;
      r.z = MOM * r.z + (1.f - MOM) * xv.z;
      r.w = MOM * r.w + (1.f - MOM) * xv.w;
      float ss = r.x * r.x + r.y * r.y + r.z * r.z + r.w * r.w;
#pragma unroll
      for (int o = 32; o > 0; o >>= 1) ss += __shfl_xor(ss, o, 64);
      float inv = 1.0f / sqrtf(ss);
      r.x *= inv; r.y *= inv; r.z *= inv; r.w *= inv;
    }
  }
  int base2 = y * Fdim + lane * 4;   // out1 is off-by-1 misaligned -> scalar stores
  out1[base2 + 0] = r.x;
  out1[base2 + 1] = r.y;
  out1[base2 + 2] = r.z;
  out1[base2 + 3] = r.w;
}

extern "C" void kernel_launch(void* const* d_in, const int* in_sizes, int n_in,
                              void* d_out, int out_size, void* d_ws, size_t ws_size,
                              hipStream_t stream) {
  const float* inputs   = (const float*)d_in[0];
  const int*   indexes  = (const int*)d_in[1];
  const float* features = (const float*)d_in[2];
  const int*   labels   = (const int*)d_in[3];
  float* out = (float*)d_out;          // out[0] = loss, out[1..] = new_features
  WS* w = (WS*)d_ws;

  k0_zero<<<4, 256, 0, stream>>>(w->counts, w->sumExp);
  k1_norm<<<Bn, 64, 0, stream>>>(inputs, indexes, labels, w->x, w->idx, w->targets);
  k2_count<<<Nn / 256, 256, 0, stream>>>(labels, w->counts);
  k3_scan<<<1, 1024, 0, stream>>>(w->counts, w->offsets, w->cursor);
  k4_fill<<<Nn / 256, 256, 0, stream>>>(labels, w->cursor, w->list);
  k5_classsum<<<Cn, 512, 0, stream>>>(features, w->list, w->offsets, w->counts,
                                      w->meanP, w->mask, out + 1);
  k6_matmul<<<dim3(Bn / BBT, 4), 256, 0, stream>>>(w->x, w->meanP, w->mask, w->targets,
                                                   w->sumExp, w->tExp);
  k7_loss<<<1, 1024, 0, stream>>>(w->sumExp, w->tExp, w->targets, out);
  k8_update<<<Bn / 4, 256, 0, stream>>>(features, w->x, w->idx, out + 1);
}

// Round 5
// 198.627 us; speedup vs baseline: 1.1062x; 1.0756x over previous
//
#include <hip/hip_runtime.h>
#include <math.h>

#define Bn   1024
#define Fdim 256
#define Nn   65536
#define Cn   1000
#define INV_TEMP 20.0f
#define MOM  0.2f

// ---------------- workspace layout (all 4-byte types, no padding) ----------
struct WS {
  float x[Bn * Fdim];       // normalized inputs                    (1 MB)
  float meanP[Fdim * Cn];   // class means, packed [F/4][Cn][4]     (1 MB)
  float mask[Cn];
  float sumExp[Bn];
  float tExp[Bn];
  int   idx[Bn];
  int   targets[Bn];
  int   counts[Cn];
  int   offsets[Cn];
  int   cursor[Cn];
  int   list[Nn];
};

// K1: x = inputs/||inputs|| (one wave per row, float4), fused with zeroing of
// counts/sumExp (blocks 0..15) and idx/target remap.
__global__ __launch_bounds__(64) void k1_norm(const float* __restrict__ inputs,
                                              const int* __restrict__ indexes,
                                              const int* __restrict__ labels,
                                              float* __restrict__ x,
                                              int* __restrict__ idx, int* __restrict__ targets,
                                              int* __restrict__ counts,
                                              float* __restrict__ sumExp) {
  int b = blockIdx.x, t = threadIdx.x;
  int g = b * 64 + t;
  if (g < Cn) counts[g] = 0;
  if (g < Bn) sumExp[g] = 0.f;
  float4 v = *(const float4*)&inputs[b * Fdim + t * 4];
  float s = v.x * v.x + v.y * v.y + v.z * v.z + v.w * v.w;
#pragma unroll
  for (int o = 32; o > 0; o >>= 1) s += __shfl_xor(s, o, 64);
  float inv = 1.0f / sqrtf(s);
  v.x *= inv; v.y *= inv; v.z *= inv; v.w *= inv;
  *(float4*)&x[b * Fdim + t * 4] = v;
  if (t == 0) {
    int i0 = indexes[b] - 1;
    if (i0 == 5554) i0 = 750;   // is_source special case -> SOURCE_CLASSES-1
    idx[b] = i0;
    targets[b] = labels[i0];
  }
}

// K2: histogram of labels (int4 loads, 4 atomics/thread)
__global__ __launch_bounds__(256) void k2_count(const int* __restrict__ labels,
                                                int* __restrict__ counts) {
  int t = blockIdx.x * blockDim.x + threadIdx.x;
  int4 l = *(const int4*)&labels[t * 4];
  atomicAdd(&counts[l.x], 1);
  atomicAdd(&counts[l.y], 1);
  atomicAdd(&counts[l.z], 1);
  atomicAdd(&counts[l.w], 1);
}

// K3: exclusive scan of counts -> offsets, cursor (single block, 1024 threads)
__global__ void k3_scan(const int* __restrict__ counts, int* __restrict__ offsets,
                        int* __restrict__ cursor) {
  __shared__ int s[1024];
  int t = threadIdx.x;
  int v = (t < Cn) ? counts[t] : 0;
  s[t] = v;
  __syncthreads();
  for (int o = 1; o < 1024; o <<= 1) {
    int a = (t >= o) ? s[t - o] : 0;
    __syncthreads();
    s[t] += a;
    __syncthreads();
  }
  if (t < Cn) {
    int off = s[t] - v;
    offsets[t] = off;
    cursor[t] = off;
  }
}

// K4: fill per-class member lists (int4 loads)
__global__ __launch_bounds__(256) void k4_fill(const int* __restrict__ labels,
                                               int* __restrict__ cursor,
                                               int* __restrict__ list) {
  int t = blockIdx.x * blockDim.x + threadIdx.x;
  int4 l = *(const int4*)&labels[t * 4];
  int n = t * 4;
  list[atomicAdd(&cursor[l.x], 1)] = n;
  list[atomicAdd(&cursor[l.y], 1)] = n + 1;
  list[atomicAdd(&cursor[l.z], 1)] = n + 2;
  list[atomicAdd(&cursor[l.w], 1)] = n + 3;
}

// K5: one block (4 waves) per class. Wave-per-row float4 gather, 2 rows in
// flight per wave. Accumulate class sum and simultaneously copy every row to
// out+1 (each row is in exactly one class list -> full bank coverage).
__global__ __launch_bounds__(256) void k5_classsum(const float* __restrict__ features,
                                                   const int* __restrict__ list,
                                                   const int* __restrict__ offsets,
                                                   const int* __restrict__ counts,
                                                   float* __restrict__ meanP,
                                                   float* __restrict__ mask,
                                                   float* __restrict__ out1) {
  int c = blockIdx.x, t = threadIdx.x, w = t >> 6, lane = t & 63;
  int off = offsets[c], cnt = counts[c];
  __shared__ int mlds[512];
  __shared__ float partial[4][256];
  float4 acc = {0.f, 0.f, 0.f, 0.f};
  for (int base = 0; base < cnt; base += 512) {
    int m = min(512, cnt - base);
    for (int i = t; i < m; i += 256) mlds[i] = list[off + base + i];
    __syncthreads();
    int i = w;
    for (; i + 4 < m; i += 8) {   // two rows per wave per iteration
      int n0 = mlds[i], n1 = mlds[i + 4];
      float4 v0 = *(const float4*)&features[n0 * Fdim + lane * 4];
      float4 v1 = *(const float4*)&features[n1 * Fdim + lane * 4];
      acc.x += v0.x + v1.x; acc.y += v0.y + v1.y;
      acc.z += v0.z + v1.z; acc.w += v0.w + v1.w;
      float* o0 = &out1[n0 * Fdim + lane * 4];
      o0[0] = v0.x; o0[1] = v0.y; o0[2] = v0.z; o0[3] = v0.w;
      float* o1 = &out1[n1 * Fdim + lane * 4];
      o1[0] = v1.x; o1[1] = v1.y; o1[2] = v1.z; o1[3] = v1.w;
    }
    for (; i < m; i += 4) {
      int n = mlds[i];
      float4 v = *(const float4*)&features[n * Fdim + lane * 4];
      acc.x += v.x; acc.y += v.y; acc.z += v.z; acc.w += v.w;
      float* o = &out1[n * Fdim + lane * 4];
      o[0] = v.x; o[1] = v.y; o[2] = v.z; o[3] = v.w;
    }
    __syncthreads();
  }
  *(float4*)&partial[w][lane * 4] = acc;
  __syncthreads();
  float s = partial[0][t] + partial[1][t] + partial[2][t] + partial[3][t];
  // packed layout: element (f=t, c) at [(f>>2)*Cn + c]*4 + (f&3)
  meanP[((t >> 2) * Cn + c) * 4 + (t & 3)] = (cnt > 0) ? s / (float)cnt : 0.f;
  if (t == 0) mask[c] = (cnt > 0) ? 1.f : 0.f;
}

// K6: sim = (x @ classMean^T)/TEMP fused with masked-softmax partials.
// BBT=4 for occupancy (grid 1024 blocks = 16 waves/CU). meanP packed so each
// thread's 4 f-elements are one coalesced dwordx4; x reads are wave-uniform.
#define BBT 4
__global__ __launch_bounds__(256) void k6_matmul(const float* __restrict__ x,
                                                 const float* __restrict__ meanP,
                                                 const float* __restrict__ mask,
                                                 const int* __restrict__ targets,
                                                 float* __restrict__ sumExp,
                                                 float* __restrict__ tExp) {
  int b0 = blockIdx.x * BBT;
  int c  = blockIdx.y * 256 + threadIdx.x;
  int lane = threadIdx.x & 63;
  bool cv = (c < Cn);
  int cc = cv ? c : 0;
  float acc[BBT];
#pragma unroll
  for (int bb = 0; bb < BBT; bb++) acc[bb] = 0.f;
  const float* xb = x + b0 * Fdim;
#pragma unroll 4
  for (int f4 = 0; f4 < Fdim / 4; f4++) {
    float4 mv = *(const float4*)&meanP[(f4 * Cn + cc) * 4];
#pragma unroll
    for (int bb = 0; bb < BBT; bb++) {
      float4 xv = *(const float4*)&xb[bb * Fdim + f4 * 4];   // uniform address
      acc[bb] = fmaf(xv.x, mv.x, acc[bb]);
      acc[bb] = fmaf(xv.y, mv.y, acc[bb]);
      acc[bb] = fmaf(xv.z, mv.z, acc[bb]);
      acc[bb] = fmaf(xv.w, mv.w, acc[bb]);
    }
  }
  float msk = cv ? mask[cc] : 0.f;
#pragma unroll
  for (int bb = 0; bb < BBT; bb++) {
    float e = msk * __expf(acc[bb] * INV_TEMP);
    float s = e;
#pragma unroll
    for (int o = 32; o > 0; o >>= 1) s += __shfl_down(s, o, 64);
    if (lane == 0) atomicAdd(&sumExp[b0 + bb], s);
    int tgt = targets[b0 + bb];
    if (cv && tgt == c) tExp[b0 + bb] = e;
  }
}

// K8: sequential momentum scatter update (blocks 0..255) + final loss
// reduction (block 256). One wave per sample b; only the first occurrence of
// each index runs, processing its whole duplicate chain in ascending b order.
__global__ __launch_bounds__(256) void k8_update(const float* __restrict__ features,
                                                 const float* __restrict__ x,
                                                 const int* __restrict__ idx,
                                                 const float* __restrict__ sumExp,
                                                 const float* __restrict__ tExp,
                                                 const int* __restrict__ targets,
                                                 float* __restrict__ out,
                                                 float* __restrict__ out1) {
  int t = threadIdx.x;
  if (blockIdx.x == 256) {          // ---- loss reduction block ----
    float a = 0.f, bsum = 0.f;
#pragma unroll
    for (int k = 0; k < 4; k++) {
      int b = t + k * 256;
      float S = sumExp[b], tE = tExp[b];
      float nll = -logf(tE / (S + 1e-6f) + 1e-6f);
      float valid = (targets[b] != 750) ? 1.f : 0.f;
      a += nll * valid; bsum += valid;
    }
#pragma unroll
    for (int o = 32; o > 0; o >>= 1) {
      a += __shfl_down(a, o, 64);
      bsum += __shfl_down(bsum, o, 64);
    }
    __shared__ float ra[4], rb[4];
    if ((t & 63) == 0) { ra[t >> 6] = a; rb[t >> 6] = bsum; }
    __syncthreads();
    if (t == 0) {
      float sa = ra[0] + ra[1] + ra[2] + ra[3];
      float sb = rb[0] + rb[1] + rb[2] + rb[3];
      out[0] = sa / fmaxf(sb, 1.f);
    }
    return;
  }
  // ---- momentum update blocks ----
  __shared__ int ilds[Bn];
  for (int i = t; i < Bn; i += 256) ilds[i] = idx[i];
  __syncthreads();
  int wid = t >> 6, lane = t & 63;
  int b = blockIdx.x * 4 + wid;
  int y = ilds[b];
  // am I the first occurrence of y?
  for (int base = 0; base < b; base += 64) {
    int j = base + lane;
    bool hit = (j < b) && (ilds[j] == y);
    if (__any(hit)) return;   // wave-uniform exit (no syncthreads below)
  }
  float4 r = *(const float4*)&features[y * Fdim + lane * 4];
  for (int base = (b >> 6) << 6; base < Bn; base += 64) {
    int k = base + lane;
    bool hit = (k >= b) && (ilds[k] == y);
    unsigned long long mbits = __ballot(hit);
    while (mbits) {
      int p = __ffsll(mbits) - 1;
      mbits &= mbits - 1;
      int kk = base + p;
      float4 xv = *(const float4*)&x[kk * Fdim + lane * 4];
      r.x = MOM * r.x + (1.f - MOM) * xv.x;
      r.y = MOM * r.y + (1.f - MOM) * xv.y;
      r.z = MOM * r.z + (1.f - MOM) * xv.z;
      r.w = MOM * r.w + (1.f - MOM) * xv.w;
      float ss = r.x * r.x + r.y * r.y + r.z * r.z + r.w * r.w;
#pragma unroll
      for (int o = 32; o > 0; o >>= 1) ss += __shfl_xor(ss, o, 64);
      float inv = 1.0f / sqrtf(ss);
      r.x *= inv; r.y *= inv; r.z *= inv; r.w *= inv;
    }
  }
  int base2 = y * Fdim + lane * 4;   // out1 is off-by-1 misaligned -> scalar stores
  out1[base2 + 0] = r.x;
  out1[base2 + 1] = r.y;
  out1[base2 + 2] = r.z;
  out1[base2 + 3] = r.w;
}

extern "C" void kernel_launch(void* const* d_in, const int* in_sizes, int n_in,
                              void* d_out, int out_size, void* d_ws, size_t ws_size,
                              hipStream_t stream) {
  const float* inputs   = (const float*)d_in[0];
  const int*   indexes  = (const int*)d_in[1];
  const float* features = (const float*)d_in[2];
  const int*   labels   = (const int*)d_in[3];
  float* out = (float*)d_out;          // out[0] = loss, out[1..] = new_features
  WS* w = (WS*)d_ws;

  k1_norm<<<Bn, 64, 0, stream>>>(inputs, indexes, labels, w->x, w->idx, w->targets,
                                 w->counts, w->sumExp);
  k2_count<<<Nn / 1024, 256, 0, stream>>>(labels, w->counts);
  k3_scan<<<1, 1024, 0, stream>>>(w->counts, w->offsets, w->cursor);
  k4_fill<<<Nn / 1024, 256, 0, stream>>>(labels, w->cursor, w->list);
  k5_classsum<<<Cn, 256, 0, stream>>>(features, w->list, w->offsets, w->counts,
                                      w->meanP, w->mask, out + 1);
  k6_matmul<<<dim3(Bn / BBT, 4), 256, 0, stream>>>(w->x, w->meanP, w->mask, w->targets,
                                                   w->sumExp, w->tExp);
  k8_update<<<Bn / 4 + 1, 256, 0, stream>>>(features, w->x, w->idx, w->sumExp, w->tExp,
                                            w->targets, out, out + 1);
}

// Round 6
// 196.625 us; speedup vs baseline: 1.1175x; 1.0102x over previous
//
#include <hip/hip_runtime.h>
#include <math.h>

#define Bn   1024
#define Fdim 256
#define Nn   65536
#define Cn   1000
#define INV_TEMP 20.0f
#define MOM  0.2f

// ---------------- workspace layout (all 4-byte types, no padding) ----------
// meanC, counts, sumExp are contiguous -> zeroed by ONE hipMemsetAsync.
struct WS {
  float x[Bn * Fdim];       // normalized inputs                    (1 MB)
  float meanP[Fdim * Cn];   // class means, packed [F/4][Cn][4]     (1 MB)
  float mask[Cn];
  float tExp[Bn];
  int   idx[Bn];
  int   targets[Bn];
  int   offsets[Cn];
  int   cursor[Cn];
  int   list[Nn];
  // ---- zero region start ----
  float meanC[Cn * Fdim];   // class sums, [c][f] layout            (1 MB)
  int   counts[Cn];
  float sumExp[Bn];
  // ---- zero region end ----
};

// K1: x = inputs/||inputs|| (one wave per row, float4) + idx/target remap.
__global__ __launch_bounds__(64) void k1_norm(const float* __restrict__ inputs,
                                              const int* __restrict__ indexes,
                                              const int* __restrict__ labels,
                                              float* __restrict__ x,
                                              int* __restrict__ idx, int* __restrict__ targets) {
  int b = blockIdx.x, t = threadIdx.x;
  float4 v = *(const float4*)&inputs[b * Fdim + t * 4];
  float s = v.x * v.x + v.y * v.y + v.z * v.z + v.w * v.w;
#pragma unroll
  for (int o = 32; o > 0; o >>= 1) s += __shfl_xor(s, o, 64);
  float inv = 1.0f / sqrtf(s);
  v.x *= inv; v.y *= inv; v.z *= inv; v.w *= inv;
  *(float4*)&x[b * Fdim + t * 4] = v;
  if (t == 0) {
    int i0 = indexes[b] - 1;
    if (i0 == 5554) i0 = 750;   // is_source special case -> SOURCE_CLASSES-1
    idx[b] = i0;
    targets[b] = labels[i0];
  }
}

// K2: histogram of labels (int4 loads, 4 atomics/thread)
__global__ __launch_bounds__(256) void k2_count(const int* __restrict__ labels,
                                                int* __restrict__ counts) {
  int t = blockIdx.x * blockDim.x + threadIdx.x;
  int4 l = *(const int4*)&labels[t * 4];
  atomicAdd(&counts[l.x], 1);
  atomicAdd(&counts[l.y], 1);
  atomicAdd(&counts[l.z], 1);
  atomicAdd(&counts[l.w], 1);
}

// K3: exclusive scan of counts -> offsets, cursor (single block, 1024 threads)
__global__ void k3_scan(const int* __restrict__ counts, int* __restrict__ offsets,
                        int* __restrict__ cursor) {
  __shared__ int s[1024];
  int t = threadIdx.x;
  int v = (t < Cn) ? counts[t] : 0;
  s[t] = v;
  __syncthreads();
  for (int o = 1; o < 1024; o <<= 1) {
    int a = (t >= o) ? s[t - o] : 0;
    __syncthreads();
    s[t] += a;
    __syncthreads();
  }
  if (t < Cn) {
    int off = s[t] - v;
    offsets[t] = off;
    cursor[t] = off;
  }
}

// K4: fill per-class member lists (int4 loads) -> list is class-sorted
__global__ __launch_bounds__(256) void k4_fill(const int* __restrict__ labels,
                                               int* __restrict__ cursor,
                                               int* __restrict__ list) {
  int t = blockIdx.x * blockDim.x + threadIdx.x;
  int4 l = *(const int4*)&labels[t * 4];
  int n = t * 4;
  list[atomicAdd(&cursor[l.x], 1)] = n;
  list[atomicAdd(&cursor[l.y], 1)] = n + 1;
  list[atomicAdd(&cursor[l.z], 1)] = n + 2;
  list[atomicAdd(&cursor[l.w], 1)] = n + 3;
}

// K5: fused bank-copy + class-sum. Linear walk over the class-sorted list:
// wave g handles entries [g*16, g*16+16). Each row (1KB) is loaded once
// (float4/lane, 8 loads in flight), copied to out+1, and accumulated into a
// per-lane float4 run-partial; on class-run boundary (wave-uniform, ~1.24
// runs/segment expected) the partial is flushed with 4 atomicAdds/lane into
// meanC[c][f] (coalesced 1KB region). 4096 waves -> uniform, deep MLP.
__global__ __launch_bounds__(256) void k5_fused(const float* __restrict__ features,
                                                const int* __restrict__ list,
                                                const int* __restrict__ labels,
                                                float* __restrict__ meanC,
                                                float* __restrict__ out1) {
  int w = blockIdx.x * 4 + (threadIdx.x >> 6);   // global wave id, 0..4095
  int lane = threadIdx.x & 63;
  int e0 = w * 16;
  float4 acc = {0.f, 0.f, 0.f, 0.f};
  int cur = -1;
#pragma unroll
  for (int bh = 0; bh < 2; bh++) {
    int r[8], cc[8];
#pragma unroll
    for (int j = 0; j < 8; j++) r[j] = list[e0 + bh * 8 + j];      // uniform
#pragma unroll
    for (int j = 0; j < 8; j++) cc[j] = labels[r[j]];              // uniform
    float4 v[8];
#pragma unroll
    for (int j = 0; j < 8; j++)
      v[j] = *(const float4*)&features[r[j] * Fdim + lane * 4];    // 8 in flight
#pragma unroll
    for (int j = 0; j < 8; j++) {
      float* o = &out1[r[j] * Fdim + lane * 4];   // +1 misaligned -> dword stores
      o[0] = v[j].x; o[1] = v[j].y; o[2] = v[j].z; o[3] = v[j].w;
      if (cc[j] != cur) {                          // wave-uniform branch
        if (cur >= 0) {
          float* p = &meanC[cur * Fdim + lane * 4];
          atomicAdd(p + 0, acc.x); atomicAdd(p + 1, acc.y);
          atomicAdd(p + 2, acc.z); atomicAdd(p + 3, acc.w);
        }
        acc.x = 0.f; acc.y = 0.f; acc.z = 0.f; acc.w = 0.f;
        cur = cc[j];
      }
      acc.x += v[j].x; acc.y += v[j].y; acc.z += v[j].z; acc.w += v[j].w;
    }
  }
  float* p = &meanC[cur * Fdim + lane * 4];
  atomicAdd(p + 0, acc.x); atomicAdd(p + 1, acc.y);
  atomicAdd(p + 2, acc.z); atomicAdd(p + 3, acc.w);
}

// K5t: meanC [c][f] -> packed meanP [f/4][c][4] with 1/count scaling + mask.
__global__ __launch_bounds__(256) void k5t_pack(const float* __restrict__ meanC,
                                                const int* __restrict__ counts,
                                                float* __restrict__ meanP,
                                                float* __restrict__ mask) {
  int c = blockIdx.x, t = threadIdx.x;
  int cnt = counts[c];
  float rc = (cnt > 0) ? 1.0f / (float)cnt : 0.f;
  float s = meanC[c * Fdim + t];
  meanP[((t >> 2) * Cn + c) * 4 + (t & 3)] = s * rc;
  if (t == 0) mask[c] = (cnt > 0) ? 1.f : 0.f;
}

// K6: sim = (x @ classMean^T)/TEMP fused with masked-softmax partials.
#define BBT 4
__global__ __launch_bounds__(256) void k6_matmul(const float* __restrict__ x,
                                                 const float* __restrict__ meanP,
                                                 const float* __restrict__ mask,
                                                 const int* __restrict__ targets,
                                                 float* __restrict__ sumExp,
                                                 float* __restrict__ tExp) {
  int b0 = blockIdx.x * BBT;
  int c  = blockIdx.y * 256 + threadIdx.x;
  int lane = threadIdx.x & 63;
  bool cv = (c < Cn);
  int cc = cv ? c : 0;
  float acc[BBT];
#pragma unroll
  for (int bb = 0; bb < BBT; bb++) acc[bb] = 0.f;
  const float* xb = x + b0 * Fdim;
#pragma unroll 4
  for (int f4 = 0; f4 < Fdim / 4; f4++) {
    float4 mv = *(const float4*)&meanP[(f4 * Cn + cc) * 4];
#pragma unroll
    for (int bb = 0; bb < BBT; bb++) {
      float4 xv = *(const float4*)&xb[bb * Fdim + f4 * 4];   // uniform address
      acc[bb] = fmaf(xv.x, mv.x, acc[bb]);
      acc[bb] = fmaf(xv.y, mv.y, acc[bb]);
      acc[bb] = fmaf(xv.z, mv.z, acc[bb]);
      acc[bb] = fmaf(xv.w, mv.w, acc[bb]);
    }
  }
  float msk = cv ? mask[cc] : 0.f;
#pragma unroll
  for (int bb = 0; bb < BBT; bb++) {
    float e = msk * __expf(acc[bb] * INV_TEMP);
    float s = e;
#pragma unroll
    for (int o = 32; o > 0; o >>= 1) s += __shfl_down(s, o, 64);
    if (lane == 0) atomicAdd(&sumExp[b0 + bb], s);
    int tgt = targets[b0 + bb];
    if (cv && tgt == c) tExp[b0 + bb] = e;
  }
}

// K8: sequential momentum scatter update (blocks 0..255) + final loss
// reduction (block 256). One wave per sample b; only the first occurrence of
// each index runs, processing its whole duplicate chain in ascending b order.
__global__ __launch_bounds__(256) void k8_update(const float* __restrict__ features,
                                                 const float* __restrict__ x,
                                                 const int* __restrict__ idx,
                                                 const float* __restrict__ sumExp,
                                                 const float* __restrict__ tExp,
                                                 const int* __restrict__ targets,
                                                 float* __restrict__ out,
                                                 float* __restrict__ out1) {
  int t = threadIdx.x;
  if (blockIdx.x == 256) {          // ---- loss reduction block ----
    float a = 0.f, bsum = 0.f;
#pragma unroll
    for (int k = 0; k < 4; k++) {
      int b = t + k * 256;
      float S = sumExp[b], tE = tExp[b];
      float nll = -logf(tE / (S + 1e-6f) + 1e-6f);
      float valid = (targets[b] != 750) ? 1.f : 0.f;
      a += nll * valid; bsum += valid;
    }
#pragma unroll
    for (int o = 32; o > 0; o >>= 1) {
      a += __shfl_down(a, o, 64);
      bsum += __shfl_down(bsum, o, 64);
    }
    __shared__ float ra[4], rb[4];
    if ((t & 63) == 0) { ra[t >> 6] = a; rb[t >> 6] = bsum; }
    __syncthreads();
    if (t == 0) {
      float sa = ra[0] + ra[1] + ra[2] + ra[3];
      float sb = rb[0] + rb[1] + rb[2] + rb[3];
      out[0] = sa / fmaxf(sb, 1.f);
    }
    return;
  }
  // ---- momentum update blocks ----
  __shared__ int ilds[Bn];
  for (int i = t; i < Bn; i += 256) ilds[i] = idx[i];
  __syncthreads();
  int wid = t >> 6, lane = t & 63;
  int b = blockIdx.x * 4 + wid;
  int y = ilds[b];
  // am I the first occurrence of y?
  for (int base = 0; base < b; base += 64) {
    int j = base + lane;
    bool hit = (j < b) && (ilds[j] == y);
    if (__any(hit)) return;   // wave-uniform exit (no syncthreads below)
  }
  float4 r = *(const float4*)&features[y * Fdim + lane * 4];
  for (int base = (b >> 6) << 6; base < Bn; base += 64) {
    int k = base + lane;
    bool hit = (k >= b) && (ilds[k] == y);
    unsigned long long mbits = __ballot(hit);
    while (mbits) {
      int p = __ffsll(mbits) - 1;
      mbits &= mbits - 1;
      int kk = base + p;
      float4 xv = *(const float4*)&x[kk * Fdim + lane * 4];
      r.x = MOM * r.x + (1.f - MOM) * xv.x;
      r.y = MOM * r.y + (1.f - MOM) * xv.y;
      r.z = MOM * r.z + (1.f - MOM) * xv.z;
      r.w = MOM * r.w + (1.f - MOM) * xv.w;
      float ss = r.x * r.x + r.y * r.y + r.z * r.z + r.w * r.w;
#pragma unroll
      for (int o = 32; o > 0; o >>= 1) ss += __shfl_xor(ss, o, 64);
      float inv = 1.0f / sqrtf(ss);
      r.x *= inv; r.y *= inv; r.z *= inv; r.w *= inv;
    }
  }
  int base2 = y * Fdim + lane * 4;   // out1 is off-by-1 misaligned -> scalar stores
  out1[base2 + 0] = r.x;
  out1[base2 + 1] = r.y;
  out1[base2 + 2] = r.z;
  out1[base2 + 3] = r.w;
}

extern "C" void kernel_launch(void* const* d_in, const int* in_sizes, int n_in,
                              void* d_out, int out_size, void* d_ws, size_t ws_size,
                              hipStream_t stream) {
  const float* inputs   = (const float*)d_in[0];
  const int*   indexes  = (const int*)d_in[1];
  const float* features = (const float*)d_in[2];
  const int*   labels   = (const int*)d_in[3];
  float* out = (float*)d_out;          // out[0] = loss, out[1..] = new_features
  WS* w = (WS*)d_ws;

  // one memset zeroes meanC + counts + sumExp (contiguous in WS)
  hipMemsetAsync(w->meanC, 0, (size_t)(Cn * Fdim + Cn + Bn) * 4, stream);
  k1_norm<<<Bn, 64, 0, stream>>>(inputs, indexes, labels, w->x, w->idx, w->targets);
  k2_count<<<Nn / 1024, 256, 0, stream>>>(labels, w->counts);
  k3_scan<<<1, 1024, 0, stream>>>(w->counts, w->offsets, w->cursor);
  k4_fill<<<Nn / 1024, 256, 0, stream>>>(labels, w->cursor, w->list);
  k5_fused<<<Nn / 64, 256, 0, stream>>>(features, w->list, labels, w->meanC, out + 1);
  k5t_pack<<<Cn, 256, 0, stream>>>(w->meanC, w->counts, w->meanP, w->mask);
  k6_matmul<<<dim3(Bn / BBT, 4), 256, 0, stream>>>(w->x, w->meanP, w->mask, w->targets,
                                                   w->sumExp, w->tExp);
  k8_update<<<Bn / 4 + 1, 256, 0, stream>>>(features, w->x, w->idx, w->sumExp, w->tExp,
                                            w->targets, out, out + 1);
}